// Round 16
// baseline (36.567 us; speedup 1.0000x reference)
//
#include <hip/hip_runtime.h>
#include <hip/hip_bf16.h>

#define BB 16
#define NN 16384
#define DD 128
#define CC 32
#define CHUNKS 16
#define NBLK (BB * CHUNKS)                  // 256
#define ROWS_PER_BLOCK (NN / CHUNKS)        // 1024

// ---- PATH A workspace layout (floats) ----
#define P_SUMS 0                                    // NBLK*4096 (4.2 MB)
#define P_CNTS ((size_t)NBLK * CC * DD)             // NBLK*32
#define LOSSP  (P_CNTS + (size_t)NBLK * CC)         // BB
#define GCTR   (LOSSP + BB)                         // 1 int
#define WS_A_FLOATS (GCTR + 1)

// ---------------- Kernel 1: segment sums (channel-interleaved streams) ------
// THEORY UNDER TEST: all prior engines gave blocks large CONTIGUOUS regions;
// at equal phase, 256 blocks alias the same HBM channels (512 KB region
// stride is a multiple of any pow2 channel interleave) -> ~4.3 TB/s cap.
// NEW: 64 row-streams per batch (16 blocks x 4 streams); stream s owns rows
// {s + 64t}. At any instant a batch's reads span one contiguous 64 KB window
// (covers all channels); batches decorrelated by rotating the group loop by b.
// Also fixes R15's collision bug: 2 rows/instr go to PARITY slabs (lanes
// 0-31 -> par 0, 32-63 -> par 1; cid is wave-uniform per half) -> no lost
// updates, absmax back to reorder-noise level.
__global__ __launch_bounds__(512) void seg_sum_kernel(
    const float* __restrict__ x, const int* __restrict__ ids,
    float* __restrict__ outsums, float* __restrict__ outcnts,
    int* __restrict__ gctr) {
  __shared__ __align__(16) float slabs[4][2][2][CC * 64]; // q,h,par: 128 KB
  __shared__ float lcnt[CC];
  __shared__ int   lcid[4][256];          // 4 KB: [stream q][t]

  const int tid  = threadIdx.x;
  const int b    = blockIdx.y;
  const int cx   = blockIdx.x;            // chunk 0..15
  const int lane = tid & 63;
  const int w    = tid >> 6;              // wave 0..7
  const int q    = w >> 1;                // row-stream 0..3
  const int h    = w & 1;                 // col-half 0..1
  const int pr   = lane >> 5;             // row parity within instr
  const int m    = lane & 31;             // lane-in-half
  const int slot = b * CHUNKS + cx;
  const int* __restrict__ idrow = ids + (size_t)b * NN;

  if (tid < CC) lcnt[tid] = 0.f;
  // stage cids for this block's 4 streams: lcid[qq][tt] = ids[cx*4+qq+64*tt]
  {
    const int e0 = tid, e1 = tid + 512;
    lcid[e0 >> 8][e0 & 255] = idrow[cx * 4 + (e0 >> 8) + 64 * (e0 & 255)];
    lcid[e1 >> 8][e1 & 255] = idrow[cx * 4 + (e1 >> 8) + 64 * (e1 & 255)];
  }
  {
    float* sb = &slabs[0][0][0][0];       // 32768 floats
    const float4 z4 = make_float4(0.f, 0.f, 0.f, 0.f);
#pragma unroll
    for (int i = 0; i < 16; ++i)
      *reinterpret_cast<float4*>(&sb[(i * 512 + tid) * 4]) = z4;
  }
  __syncthreads();
  {
    const int e0 = tid, e1 = tid + 512;
    atomicAdd(&lcnt[lcid[e0 >> 8][e0 & 255]], 1.f);
    atomicAdd(&lcnt[lcid[e1 >> 8][e1 & 255]], 1.f);
  }

  // stream base row: s = cx*4 + q; instr u covers rows s+64*(2u+pr)
  const int srow = cx * 4 + q;
  const float2* __restrict__ x2 =
      reinterpret_cast<const float2*>(x + (size_t)b * NN * DD);
  float* const sl = &slabs[q][h][pr][0];
  const int colo = h * 32 + m;            // float2 col index within row

  float2 vA[8], vB[8];
  int cA[8], cB[8];

#define LOADG(V, C, g)                                                     \
  {                                                                        \
    const int ge = ((g) + b) & 15;        /* batch-staggered phase */      \
    _Pragma("unroll") for (int k = 0; k < 8; ++k) {                        \
      const int t = 2 * (ge * 8 + k) + pr;                                 \
      V[k] = x2[(size_t)(srow + 64 * t) * 64 + colo];                      \
      C[k] = lcid[q][t];                                                   \
    }                                                                      \
  }
#define RMWG(V, C)                                                         \
  {                                                                        \
    _Pragma("unroll") for (int k = 0; k < 8; ++k) {                        \
      float2* p = reinterpret_cast<float2*>(&sl[C[k] * 64 + 2 * m]);       \
      float2 old = *p;                                                     \
      *p = make_float2(old.x + V[k].x, old.y + V[k].y);                    \
    }                                                                      \
  }

  LOADG(vA, cA, 0)                        // 16 groups x 8 instrs (128/wave)
#pragma unroll
  for (int i = 0; i < 7; ++i) {
    LOADG(vB, cB, 2 * i + 1)
    RMWG(vA, cA)
    LOADG(vA, cA, 2 * i + 2)
    RMWG(vB, cB)
  }
  LOADG(vB, cB, 15)
  RMWG(vA, cA)                            // group 14
  RMWG(vB, cB)                            // group 15
#undef LOADG
#undef RMWG
  __syncthreads();

  // epilogue: fold 4 streams x 2 parities per col-half -> 16 KB partial
  float* __restrict__ ps = outsums + (size_t)slot * CC * DD;
#pragma unroll
  for (int it = 0; it < 8; ++it) {
    const int idx = it * 512 + tid;       // c*128 + h2*64 + j
    const int c  = idx >> 7;
    const int r  = idx & 127;
    const int h2 = r >> 6;
    const int j  = r & 63;
    const int o  = c * 64 + j;
    float s = 0.f;
#pragma unroll
    for (int qq = 0; qq < 4; ++qq)
      s += slabs[qq][h2][0][o] + slabs[qq][h2][1][o];
    ps[idx] = s;
  }
  if (tid < CC) outcnts[slot * CC + tid] = lcnt[tid];
  if (slot == 0 && tid == 0)
    __hip_atomic_store(gctr, 0, __ATOMIC_RELAXED, __HIP_MEMORY_SCOPE_AGENT);
}

// ---------------- Kernel 2: fused reduce + gram + final (proven) ------------
#define MSTR 132
__global__ __launch_bounds__(512) void finish_fused_kernel(
    const float* __restrict__ psums, const float* __restrict__ pcnts,
    float* __restrict__ lossp, int* __restrict__ gctr,
    float* __restrict__ out) {
  __shared__ float mean[CC * MSTR];
  __shared__ float cnt[CC];
  __shared__ float red[512];

  const int b = blockIdx.x;
  const int tid = threadIdx.x;

  if (tid < CC) {
    float cs = 0.f;
#pragma unroll
    for (int c = 0; c < CHUNKS; ++c) cs += pcnts[(b * CHUNKS + c) * CC + tid];
    cnt[tid] = cs;
  }

  float4 a0 = make_float4(0.f, 0.f, 0.f, 0.f), a1 = a0;
  const size_t base = (size_t)b * CHUNKS * CC * DD + (size_t)tid * 8;
#pragma unroll 4
  for (int c = 0; c < CHUNKS; ++c) {
    const float4* p = reinterpret_cast<const float4*>(&psums[base + (size_t)c * CC * DD]);
    float4 q0 = p[0], q1 = p[1];
    a0.x += q0.x; a0.y += q0.y; a0.z += q0.z; a0.w += q0.w;
    a1.x += q1.x; a1.y += q1.y; a1.z += q1.z; a1.w += q1.w;
  }
  __syncthreads();

  {
    const int c = tid >> 4;
    const int d0 = (tid & 15) * 8;
    const float inv = 1.f / fmaxf(cnt[c], 1.f);
    float* mrow = &mean[c * MSTR + d0];
    mrow[0] = a0.x * inv; mrow[1] = a0.y * inv; mrow[2] = a0.z * inv; mrow[3] = a0.w * inv;
    mrow[4] = a1.x * inv; mrow[5] = a1.y * inv; mrow[6] = a1.z * inv; mrow[7] = a1.w * inv;
  }
  __syncthreads();

  float acc = 0.f;
  if (tid < (CC * (CC - 1)) / 2) {
    int c = 0, rem = tid;
    while (rem >= (CC - 1 - c)) { rem -= (CC - 1 - c); ++c; }
    int e = c + 1 + rem;
    const float4* mc = reinterpret_cast<const float4*>(&mean[c * MSTR]);
    const float4* me = reinterpret_cast<const float4*>(&mean[e * MSTR]);
    float dot = 0.f;
#pragma unroll 8
    for (int j = 0; j < DD / 4; ++j) {
      float4 u = mc[j], v = me[j];
      dot += u.x * v.x + u.y * v.y + u.z * v.z + u.w * v.w;
    }
    acc = fabsf(dot);
  }

  red[tid] = acc;
  __syncthreads();
  for (int s = 256; s > 0; s >>= 1) {
    if (tid < s) red[tid] += red[tid + s];
    __syncthreads();
  }

  if (tid == 0) {
    float valid = 0.f;
    for (int c = 0; c < CC; ++c) valid += (cnt[c] > 0.f) ? 1.f : 0.f;
    float denom = (valid > 1.f) ? valid * (valid - 1.f) * 0.5f : 1.f;
    float v = red[0] / denom * (1.0f / BB);
    __hip_atomic_store(&lossp[b], v, __ATOMIC_RELAXED, __HIP_MEMORY_SCOPE_AGENT);
    __threadfence();
    int old = __hip_atomic_fetch_add(gctr, 1, __ATOMIC_ACQ_REL,
                                     __HIP_MEMORY_SCOPE_AGENT);
    if (old == BB - 1) {
      __threadfence();
      float s = 0.f;
#pragma unroll
      for (int i = 0; i < BB; ++i)
        s += __hip_atomic_load(&lossp[i], __ATOMIC_RELAXED,
                               __HIP_MEMORY_SCOPE_AGENT);
      out[0] = s;
    }
  }
}

// ---------------- PATH B fallback (atomic accumulate) -----------------------
#define RPB_B 512
#define ROWS_PER_WAVE_B 128
__global__ __launch_bounds__(256) void seg_sum_rmw_b(
    const float* __restrict__ x, const int* __restrict__ ids,
    float* __restrict__ gsums, float* __restrict__ gcounts) {
  __shared__ float lsum[4][CC * DD];
  __shared__ float lcnt[CC];
  __shared__ int   lcid[RPB_B];

  const int tid  = threadIdx.x;
  const int b    = blockIdx.y;
  const int row0 = blockIdx.x * RPB_B;
  const int lane = tid & 63;
  const int w    = tid >> 6;
  const int* __restrict__ idrow = ids + (size_t)b * NN;

  if (tid < CC) lcnt[tid] = 0.f;
  lcid[tid]       = idrow[row0 + tid];
  lcid[tid + 256] = idrow[row0 + tid + 256];
  {
    const float4 z4 = make_float4(0.f, 0.f, 0.f, 0.f);
#pragma unroll
    for (int i = 0; i < 16; ++i)
      *reinterpret_cast<float4*>(&lsum[w][(i * 64 + lane) * 4]) = z4;
  }
  __syncthreads();
  atomicAdd(&lcnt[lcid[tid]], 1.f);
  atomicAdd(&lcnt[lcid[tid + 256]], 1.f);

  const float2* __restrict__ x2 =
      reinterpret_cast<const float2*>(x + (size_t)b * NN * DD);
  const int wbase = w * ROWS_PER_WAVE_B;
  float* const slab = &lsum[w][0];

  for (int g = 0; g < ROWS_PER_WAVE_B / 8; ++g) {
    float2 v[8]; int cid[8];
#pragma unroll
    for (int k = 0; k < 8; ++k) {
      const int rl = wbase + g * 8 + k;
      v[k]   = x2[(size_t)(row0 + rl) * 64 + lane];
      cid[k] = lcid[rl];
    }
#pragma unroll
    for (int k = 0; k < 8; ++k) {
      float2* p = reinterpret_cast<float2*>(&slab[cid[k] * DD + 2 * lane]);
      float2 old = *p;
      *p = make_float2(old.x + v[k].x, old.y + v[k].y);
    }
  }
  __syncthreads();

  float* __restrict__ gs = gsums + (size_t)b * CC * DD;
  for (int i = tid; i < CC * DD; i += 256) {
    float s = lsum[0][i] + lsum[1][i] + lsum[2][i] + lsum[3][i];
    atomicAdd(&gs[i], s);
  }
  if (tid < CC) atomicAdd(&gcounts[b * CC + tid], lcnt[tid]);
}

__global__ __launch_bounds__(512) void finish_kernel_b(
    const float* __restrict__ gsums, const float* __restrict__ gcounts,
    float* __restrict__ out) {
  __shared__ float mean[CC * MSTR];
  __shared__ float cnt[CC];
  __shared__ float red[512];

  const int b = blockIdx.x;
  const int tid = threadIdx.x;

  if (tid < CC) cnt[tid] = gcounts[b * CC + tid];
  __syncthreads();
  for (int i = tid; i < CC * DD; i += 512) {
    int c = i >> 7;
    int d = i & 127;
    mean[c * MSTR + d] = gsums[(size_t)b * CC * DD + i] / fmaxf(cnt[c], 1.f);
  }
  __syncthreads();

  float acc = 0.f;
  if (tid < (CC * (CC - 1)) / 2) {
    int c = 0, rem = tid;
    while (rem >= (CC - 1 - c)) { rem -= (CC - 1 - c); ++c; }
    int e = c + 1 + rem;
    const float4* mc = reinterpret_cast<const float4*>(&mean[c * MSTR]);
    const float4* me = reinterpret_cast<const float4*>(&mean[e * MSTR]);
    float dot = 0.f;
#pragma unroll 8
    for (int jj = 0; jj < DD / 4; ++jj) {
      float4 u = mc[jj], v = me[jj];
      dot += u.x * v.x + u.y * v.y + u.z * v.z + u.w * v.w;
    }
    acc = fabsf(dot);
  }
  red[tid] = acc;
  __syncthreads();
  for (int s = 256; s > 0; s >>= 1) {
    if (tid < s) red[tid] += red[tid + s];
    __syncthreads();
  }
  if (tid == 0) {
    float valid = 0.f;
    for (int c = 0; c < CC; ++c) valid += (cnt[c] > 0.f) ? 1.f : 0.f;
    float denom = (valid > 1.f) ? valid * (valid - 1.f) * 0.5f : 1.f;
    atomicAdd(out, red[0] / denom * (1.0f / BB));
  }
}

extern "C" void kernel_launch(void* const* d_in, const int* in_sizes, int n_in,
                              void* d_out, int out_size, void* d_ws, size_t ws_size,
                              hipStream_t stream) {
  const float* x   = (const float*)d_in[0];
  const int*   ids = (const int*)d_in[1];
  float* out = (float*)d_out;
  float* ws  = (float*)d_ws;

  if (ws_size >= WS_A_FLOATS * sizeof(float)) {
    float* psums = ws + P_SUMS;
    float* pcnts = ws + P_CNTS;
    float* lossp = ws + LOSSP;
    int*   gctr  = (int*)(ws + GCTR);
    dim3 grid1(CHUNKS, BB);
    seg_sum_kernel<<<grid1, 512, 0, stream>>>(x, ids, psums, pcnts, gctr);
    finish_fused_kernel<<<BB, 512, 0, stream>>>(psums, pcnts, lossp, gctr, out);
  } else {
    float* gsums   = ws;
    float* gcounts = gsums + (size_t)BB * CC * DD;
    const size_t wsb = ((size_t)BB * CC * DD + (size_t)BB * CC) * sizeof(float);
    hipMemsetAsync(d_ws, 0, wsb, stream);
    hipMemsetAsync(d_out, 0, sizeof(float), stream);
    dim3 gridb(NN / RPB_B, BB);
    seg_sum_rmw_b<<<gridb, 256, 0, stream>>>(x, ids, gsums, gcounts);
    finish_kernel_b<<<BB, 512, 0, stream>>>(gsums, gcounts, out);
  }
}